// Round 16
// baseline (119.751 us; speedup 1.0000x reference)
//
#include <hip/hip_runtime.h>
#include <hip/hip_bf16.h>
#include <math.h>

// Sparsemax over rows of [N_ROWS, 64] fp32 — persistent waves, software-
// pipelined tiles: prefetch next tile's loads into registers while iterating
// the current tile. Pair-per-row register Michelot, LDS transpose buffer,
// no barriers (wave-private 8KB LDS slice).
//
// Ladder: r8 145us (scattered VMEM) -> r10 102.7 (coalesced) -> r12 84.6
// (LDS transpose + reg Michelot) -> r13 81.4 (no barriers / no result-write;
// conflicts 0, no spills) -> r15 83.6 (block=64 regressed: dispatch overhead).
// r13 residual: per-wave serialization load->compute->store. This round:
// grid-stride persistent waves, next-tile global loads issued right after
// pair-read so ~900cy HBM latency hides under iterate+stage-out (~1200cy).
// launch_bounds(256,4): 128-VGPR budget for L(32)+v(32)+misc; LDS caps
// occupancy at 5 blocks/CU regardless, so the budget is free.
//
// FROZEN r13 iteration arithmetic (r14 lesson: max-fold cancellation flipped
// support boundaries; sub/max/add order must not change).
// Michelot fixed point (z=1 simplex threshold), all decisions fp32
// (r6: fp16 flipped the support boundary -> 1/rho output jumps):
//   tau0 = max(x)-1 ; tau += (sum(max(0,x-tau))-1)/c ; stop when c fixed.
//   reference's double -1: tau_out = tau* - 1/rho ; out = max(0, x - tau_out)

typedef float nfloat4 __attribute__((ext_vector_type(4)));

#define FOR8(OP) OP(0) OP(1) OP(2) OP(3) OP(4) OP(5) OP(6) OP(7)

__device__ __forceinline__ nfloat4 v4max(nfloat4 a, nfloat4 b) {
    nfloat4 r;
    r.x = fmaxf(a.x, b.x); r.y = fmaxf(a.y, b.y);
    r.z = fmaxf(a.z, b.z); r.w = fmaxf(a.w, b.w);
    return r;
}

__global__ __launch_bounds__(256, 4) void sparsemax_pipe(
    const float* __restrict__ x, float* __restrict__ out, long long n_rows) {
    __shared__ nfloat4 lds4[4][512];              // 8 KB per wave, wave-private
    const int lane = threadIdx.x & 63;
    const int w = threadIdx.x >> 6;
    nfloat4* W = lds4[w];

    const nfloat4* __restrict__ xv = reinterpret_cast<const nfloat4*>(x);
    nfloat4* __restrict__ ov = reinterpret_cast<nfloat4*>(out);
    const long long f4max = n_rows * 16;
    const long long ntiles = (n_rows + 31) >> 5;  // 32 rows per tile
    const long long nwaves = (long long)gridDim.x * 4;

    const int hi4 = lane >> 4;
    const int l15 = lane & 15;
    const int prow = lane >> 1;                   // tile-local row of this pair
    const int s7 = prow & 7;
    const int pbase = prow * 16 + (lane & 1) * 8; // this lane's half-row base

    long long tile = (long long)blockIdx.x * 4 + w;
    if (tile >= ntiles) return;

    nfloat4 L0, L1, L2, L3, L4, L5, L6, L7;       // staging regs (next tile)

#define LOADL(T) {                                                        \
        const long long gb = (T) * 512;                                   \
        if (gb + 512 <= f4max) {                                          \
            L0 = xv[gb + 0 * 64 + lane]; L1 = xv[gb + 1 * 64 + lane];     \
            L2 = xv[gb + 2 * 64 + lane]; L3 = xv[gb + 3 * 64 + lane];     \
            L4 = xv[gb + 4 * 64 + lane]; L5 = xv[gb + 5 * 64 + lane];     \
            L6 = xv[gb + 6 * 64 + lane]; L7 = xv[gb + 7 * 64 + lane];     \
        } else {                                                          \
            const nfloat4 z = {0.f, 0.f, 0.f, 0.f};                       \
            L0 = (gb + 0 * 64 + lane < f4max) ? xv[gb + 0 * 64 + lane] : z; \
            L1 = (gb + 1 * 64 + lane < f4max) ? xv[gb + 1 * 64 + lane] : z; \
            L2 = (gb + 2 * 64 + lane < f4max) ? xv[gb + 2 * 64 + lane] : z; \
            L3 = (gb + 3 * 64 + lane < f4max) ? xv[gb + 3 * 64 + lane] : z; \
            L4 = (gb + 4 * 64 + lane < f4max) ? xv[gb + 4 * 64 + lane] : z; \
            L5 = (gb + 5 * 64 + lane < f4max) ? xv[gb + 5 * 64 + lane] : z; \
            L6 = (gb + 6 * 64 + lane < f4max) ? xv[gb + 6 * 64 + lane] : z; \
            L7 = (gb + 7 * 64 + lane < f4max) ? xv[gb + 7 * 64 + lane] : z; \
        }                                                                 \
    }

    LOADL(tile)   // prologue: first tile has no overlap (startup cost only)

    for (;;) {
        // ---- ds_write staging regs -> W (swizzled, conflict-free) ----
#define DSW(i) { const int r = i * 4 + hi4; W[r * 16 + (l15 ^ (r & 7))] = L##i; }
        FOR8(DSW)
#undef DSW
        asm volatile("" ::: "memory");   // writes before pair-reads

        // ---- pair-read: half-row (32 floats) into pinned registers ----
#define PR(j) nfloat4 v##j = W[pbase + (j ^ s7)];
        FOR8(PR)
#undef PR
#define PIN(j) asm volatile("" : "+v"(v##j.x), "+v"(v##j.y), "+v"(v##j.z), "+v"(v##j.w));
        FOR8(PIN)
#undef PIN

        // ---- prefetch next tile into L: issues here, lands during
        //      iterate + stage-out (no waits until next DSW) ----
        const long long nt = tile + nwaves;
        const bool have_next = nt < ntiles;      // wave-uniform
        if (have_next) LOADL(nt)
        asm volatile("" ::: "memory");   // pin load issue point; no waitcnt

        // ---- row max (local 31 + 1 pair-combine) -> tau0 = max - 1 ----
        nfloat4 m4 = v4max(v4max(v4max(v0, v1), v4max(v2, v3)),
                           v4max(v4max(v4, v5), v4max(v6, v7)));
        float m = fmaxf(fmaxf(m4.x, m4.y), fmaxf(m4.z, m4.w));
        m = fmaxf(m, __shfl_xor(m, 1, 64));

        float tau = m - 1.0f;
        int cprev = -1;                 // force at least one iteration
        float rfin = 1.0f;
        for (int it = 0; it < 40; ++it) {
            // FROZEN r13 arithmetic: s = sum(max(x - tau, 0)), same order
            float s0 = 0.f, s1 = 0.f;
            int c0 = 0, c1 = 0;
#define ACC(j) {                                              \
            const float d0 = v##j.x - tau, d1 = v##j.y - tau; \
            const float d2 = v##j.z - tau, d3 = v##j.w - tau; \
            s0 += fmaxf(d0, 0.f); c0 += (d0 > 0.f);           \
            s1 += fmaxf(d1, 0.f); c1 += (d1 > 0.f);           \
            s0 += fmaxf(d2, 0.f); c0 += (d2 > 0.f);           \
            s1 += fmaxf(d3, 0.f); c1 += (d3 > 0.f); }
            FOR8(ACC)
#undef ACC
            float s = s0 + s1;
            int c = c0 + c1;
            // pair combine (DPP quad_perm; commutative -> identical in pair)
            s += __shfl_xor(s, 1, 64);
            c += __shfl_xor(c, 1, 64);
            const bool done = (c == cprev);   // nested supports: count fixed
            cprev = c;
            const float rr = __builtin_amdgcn_rcpf((float)c);
            rfin = rr;
            tau += (s - 1.0f) * rr;           // idempotent once converged
            if (__all(done)) break;
        }
        const float tau_out = tau - rfin;     // reference double -1: tau*-1/rho

        asm volatile("" ::: "memory");   // iterate before stage-out reads

        // ---- stage-out: originals from W + tau via shfl -> coalesced NT store ----
        {
            const long long gb = tile * 512;
            if (gb + 512 <= f4max) {
#pragma unroll
                for (int i = 0; i < 8; ++i) {
                    const int r = i * 4 + hi4;
                    const float tr = __shfl(tau_out, 8 * i + 2 * hi4, 64);
                    const nfloat4 vv = W[r * 16 + (l15 ^ (r & 7))];
                    nfloat4 t;
                    t.x = fmaxf(0.f, vv.x - tr);
                    t.y = fmaxf(0.f, vv.y - tr);
                    t.z = fmaxf(0.f, vv.z - tr);
                    t.w = fmaxf(0.f, vv.w - tr);
                    __builtin_nontemporal_store(t, &ov[gb + i * 64 + lane]);
                }
            } else {
#pragma unroll
                for (int i = 0; i < 8; ++i) {
                    const int r = i * 4 + hi4;
                    const float tr = __shfl(tau_out, 8 * i + 2 * hi4, 64);
                    const nfloat4 vv = W[r * 16 + (l15 ^ (r & 7))];
                    nfloat4 t;
                    t.x = fmaxf(0.f, vv.x - tr);
                    t.y = fmaxf(0.f, vv.y - tr);
                    t.z = fmaxf(0.f, vv.z - tr);
                    t.w = fmaxf(0.f, vv.w - tr);
                    if (gb + i * 64 + lane < f4max)
                        __builtin_nontemporal_store(t, &ov[gb + i * 64 + lane]);
                }
            }
        }

        if (!have_next) break;
        tile = nt;
        asm volatile("" ::: "memory");   // stage-out reads before next ds_write
    }
#undef LOADL
}

extern "C" void kernel_launch(void* const* d_in, const int* in_sizes, int n_in,
                              void* d_out, int out_size, void* d_ws, size_t ws_size,
                              hipStream_t stream) {
    const float* x = (const float*)d_in[0];
    float* out = (float*)d_out;
    const long long n_rows = in_sizes[0] / 64;
    const long long ntiles = (n_rows + 31) / 32;

    const int block = 256;                        // 4 independent waves / block
    long long grid = (ntiles + 3) / 4;            // enough waves to cover tiles
    if (grid > 1280) grid = 1280;                 // 5 blocks/CU resident (LDS cap)
    sparsemax_pipe<<<(int)grid, block, 0, stream>>>(x, out, n_rows);
}

// Round 17
// 105.515 us; speedup vs baseline: 1.1349x; 1.1349x over previous
//
#include <hip/hip_runtime.h>
#include <hip/hip_bf16.h>
#include <math.h>

// Sparsemax over rows of [N_ROWS, 64] fp32 — double-buffered async prefetch
// via global_load_lds (ZERO staging registers), pair-per-row register
// Michelot, wave-private LDS, counted vmcnt (never 0 in steady state).
//
// Ladder: r10 102.7 (coalesced) -> r12 84.6 (LDS transpose + reg Michelot)
// -> r13 81.4 (no barriers) -> r15 83.6 (block=64 regressed) -> r16 119.7
// (register prefetch: allocator capped at 64 VGPR, spilled the staging regs).
// LESSON: the allocator refuses >64 VGPRs — prefetch must use NO registers.
// global_load_lds stages HBM->LDS directly (16B/lane); the LDS swizzle is
// preserved by PRE-SWIZZLING the per-lane global source (gload writes LDS
// linearly at base+lane*16; source permutation == the involution; XOR within
// 16 lanes keeps the 64B-segment set minimal so coalescing is unchanged).
//
// FROZEN r13 iteration arithmetic (r14: max-fold cancellation flipped
// support boundaries -> 1/rho output jumps; sub/max/add order fixed).
// Michelot fixed point (z=1 simplex threshold), all decisions fp32:
//   tau0 = max(x)-1 ; tau += (sum(max(0,x-tau))-1)/c ; stop when c fixed.
//   reference's double -1: tau_out = tau* - 1/rho ; out = max(0, x - tau_out)

typedef float nfloat4 __attribute__((ext_vector_type(4)));

#define FOR8(OP) OP(0) OP(1) OP(2) OP(3) OP(4) OP(5) OP(6) OP(7)

__device__ __forceinline__ nfloat4 v4max(nfloat4 a, nfloat4 b) {
    nfloat4 r;
    r.x = fmaxf(a.x, b.x); r.y = fmaxf(a.y, b.y);
    r.z = fmaxf(a.z, b.z); r.w = fmaxf(a.w, b.w);
    return r;
}

__global__ __launch_bounds__(128) void sparsemax_dbuf(
    const float* __restrict__ x, float* __restrict__ out, long long n_rows) {
    __shared__ nfloat4 lds4[2][2][512];           // [wave][dbuf][8KB tile]
    const int lane = threadIdx.x & 63;
    const int w = threadIdx.x >> 6;

    const long long ntiles = (n_rows + 31) >> 5;  // 32 rows per tile
    const long long nwaves = (long long)gridDim.x * 2;
    const long long f4max = n_rows * 16;

    const int hi4 = lane >> 4;
    const int l15 = lane & 15;
    const int prow = lane >> 1;                   // tile-local row of this pair
    const int s7 = prow & 7;
    const int pbase = prow * 16 + (lane & 1) * 8; // this lane's half-row base

    const nfloat4* __restrict__ xv = reinterpret_cast<const nfloat4*>(x);
    nfloat4* __restrict__ ov = reinterpret_cast<nfloat4*>(out);

    long long t = (long long)blockIdx.x * 2 + w;
    if (t >= ntiles) return;

    // ---- async stage: 8x global_load_lds, pre-swizzled per-lane source ----
    // LDS[p_hw] gets x[gb + p_swz(p_hw)]; p_swz = involution r*16+(q^(r&7)).
#define ISSUE(T, B) {                                                     \
        const long long gb = (T) * 512;                                   \
        _Pragma("unroll")                                                 \
        for (int i = 0; i < 8; ++i) {                                     \
            const int r = i * 4 + hi4;                                    \
            const long long fsrc = gb + r * 16 + (l15 ^ (r & 7));         \
            __builtin_amdgcn_global_load_lds(                             \
                (const __attribute__((address_space(1))) unsigned int*)(xv + fsrc), \
                (__attribute__((address_space(3))) unsigned int*)((B) + i * 64),    \
                16, 0, 0);                                                \
        }                                                                 \
    }

    bool curFull = (t * 32 + 32) <= n_rows;
    int cur = 0;
    if (curFull) ISSUE(t, lds4[w][0])

    for (;;) {
        nfloat4* W = lds4[w][cur];
        const long long nt = t + nwaves;
        const bool haveNext = nt < ntiles;                       // wave-uniform
        const bool nextFull = haveNext && ((nt * 32 + 32) <= n_rows);
        if (nextFull) ISSUE(nt, lds4[w][cur ^ 1])

        if (curFull) {
            // counted wait: only the 8 just-issued loads may stay in flight
            if (nextFull) { asm volatile("s_waitcnt vmcnt(8)" ::: "memory"); }
            else          { asm volatile("s_waitcnt vmcnt(0)" ::: "memory"); }
            __builtin_amdgcn_sched_barrier(0);
        } else {
            // partial tail tile: manual bounded stage (never hit when N%32==0)
            const long long gb = t * 512;
#pragma unroll
            for (int i = 0; i < 8; ++i) {
                const int r = i * 4 + hi4;
                nfloat4 tv = {0.f, 0.f, 0.f, 0.f};
                if (gb + i * 64 + lane < f4max) tv = xv[gb + i * 64 + lane];
                W[r * 16 + (l15 ^ (r & 7))] = tv;
            }
            asm volatile("" ::: "memory");
        }

        // ---- pair-read: half-row (32 floats) into pinned registers ----
#define PR(j) nfloat4 v##j = W[pbase + (j ^ s7)];
        FOR8(PR)
#undef PR
#define PIN(j) asm volatile("" : "+v"(v##j.x), "+v"(v##j.y), "+v"(v##j.z), "+v"(v##j.w));
        FOR8(PIN)
#undef PIN

        // ---- row max (local 31 + 1 pair-combine) -> tau0 = max - 1 ----
        nfloat4 m4 = v4max(v4max(v4max(v0, v1), v4max(v2, v3)),
                           v4max(v4max(v4, v5), v4max(v6, v7)));
        float m = fmaxf(fmaxf(m4.x, m4.y), fmaxf(m4.z, m4.w));
        m = fmaxf(m, __shfl_xor(m, 1, 64));

        float tau = m - 1.0f;
        int cprev = -1;                 // force at least one iteration
        float rfin = 1.0f;
        for (int it = 0; it < 40; ++it) {
            // FROZEN r13 arithmetic: s = sum(max(x - tau, 0)), same order
            float s0 = 0.f, s1 = 0.f;
            int c0 = 0, c1 = 0;
#define ACC(j) {                                              \
            const float d0 = v##j.x - tau, d1 = v##j.y - tau; \
            const float d2 = v##j.z - tau, d3 = v##j.w - tau; \
            s0 += fmaxf(d0, 0.f); c0 += (d0 > 0.f);           \
            s1 += fmaxf(d1, 0.f); c1 += (d1 > 0.f);           \
            s0 += fmaxf(d2, 0.f); c0 += (d2 > 0.f);           \
            s1 += fmaxf(d3, 0.f); c1 += (d3 > 0.f); }
            FOR8(ACC)
#undef ACC
            float s = s0 + s1;
            int c = c0 + c1;
            // pair combine (DPP quad_perm; commutative -> identical in pair)
            s += __shfl_xor(s, 1, 64);
            c += __shfl_xor(c, 1, 64);
            const bool done = (c == cprev);   // nested supports: count fixed
            cprev = c;
            const float rr = __builtin_amdgcn_rcpf((float)c);
            rfin = rr;
            tau += (s - 1.0f) * rr;           // idempotent once converged
            if (__all(done)) break;
        }
        const float tau_out = tau - rfin;     // reference double -1: tau*-1/rho

        asm volatile("" ::: "memory");   // iterate before stage-out reads

        // ---- stage-out: originals from W + tau via shfl -> coalesced NT store ----
        {
            const long long gb = t * 512;
            if (curFull) {
#pragma unroll
                for (int i = 0; i < 8; ++i) {
                    const int r = i * 4 + hi4;
                    const float tr = __shfl(tau_out, 8 * i + 2 * hi4, 64);
                    const nfloat4 vv = W[r * 16 + (l15 ^ (r & 7))];
                    nfloat4 o;
                    o.x = fmaxf(0.f, vv.x - tr);
                    o.y = fmaxf(0.f, vv.y - tr);
                    o.z = fmaxf(0.f, vv.z - tr);
                    o.w = fmaxf(0.f, vv.w - tr);
                    __builtin_nontemporal_store(o, &ov[gb + i * 64 + lane]);
                }
            } else {
#pragma unroll
                for (int i = 0; i < 8; ++i) {
                    const int r = i * 4 + hi4;
                    const float tr = __shfl(tau_out, 8 * i + 2 * hi4, 64);
                    const nfloat4 vv = W[r * 16 + (l15 ^ (r & 7))];
                    nfloat4 o;
                    o.x = fmaxf(0.f, vv.x - tr);
                    o.y = fmaxf(0.f, vv.y - tr);
                    o.z = fmaxf(0.f, vv.z - tr);
                    o.w = fmaxf(0.f, vv.w - tr);
                    if (gb + i * 64 + lane < f4max)
                        __builtin_nontemporal_store(o, &ov[gb + i * 64 + lane]);
                }
            }
        }

        if (!haveNext) break;
        t = nt;
        curFull = nextFull;
        cur ^= 1;
        asm volatile("" ::: "memory");   // stage-out reads before buffer reuse
    }
#undef ISSUE
}

extern "C" void kernel_launch(void* const* d_in, const int* in_sizes, int n_in,
                              void* d_out, int out_size, void* d_ws, size_t ws_size,
                              hipStream_t stream) {
    const float* x = (const float*)d_in[0];
    float* out = (float*)d_out;
    const long long n_rows = in_sizes[0] / 64;
    const long long ntiles = (n_rows + 31) / 32;

    const int block = 128;                        // 2 waves, 32KB LDS/block
    long long grid = (ntiles + 1) / 2;
    if (grid > 1280) grid = 1280;                 // 5 blocks/CU resident
    sparsemax_dbuf<<<(int)grid, block, 0, stream>>>(x, out, n_rows);
}

// Round 18
// 81.960 us; speedup vs baseline: 1.4611x; 1.2874x over previous
//
#include <hip/hip_runtime.h>
#include <hip/hip_bf16.h>
#include <math.h>

// Sparsemax over rows of [N_ROWS, 64] fp32 — QUAD-PER-ROW (4 lanes/row,
// 16 rows/wave, 4KB LDS/wave) to hit the 32-waves/CU hardware occupancy cap.
//
// Ladder: r10 102.7 (coalesced) -> r12 84.6 (LDS transpose + reg Michelot)
// -> r13 81.4 (no barriers; VALU 33%, 4.94 TB/s, occ 34% @ 20-waves/CU LDS
// cap) -> r15/r16/r17 pipelining attempts ALL regressed (83.6/119.7/105.5):
// occupancy-driven wave overlap beats source pipelining for this op.
// This round: halve LDS per wave (8KB->4KB) by splitting rows 4-ways instead
// of 2-ways -> LDS cap 40 waves/CU -> HW cap 32 waves/CU (+60% TLP vs r13).
// Quad combine = 2 intra-quad DPP shuffles (xor 1, xor 2) per quantity.
//
// Swizzle p = row*16 + (c ^ (row&7)) (f4 units) is uniform (8 lanes per
// 16B bank-quad) in all four LDS phases: linear stage-in write, quad-read
// (lane reads c = q*4+j, j=0..3), and linear stage-out read.
//
// FROZEN per-value iteration arithmetic (r14: max-fold cancellation flipped
// support boundaries -> 1/rho output jumps): d = x - tau; max(d,0); (d>0).
// Michelot fixed point (z=1 simplex threshold), all decisions fp32
// (r6: fp16 flipped boundaries):
//   tau0 = max(x)-1 ; tau += (sum(max(0,x-tau))-1)/c ; stop when c fixed
//   (supports nested/shrinking; update idempotent at the fixed point).
//   reference's double -1: tau_out = tau* - 1/rho ; out = max(0, x - tau_out)

typedef float nfloat4 __attribute__((ext_vector_type(4)));

#define FOR4(OP) OP(0) OP(1) OP(2) OP(3)

__device__ __forceinline__ nfloat4 v4max(nfloat4 a, nfloat4 b) {
    nfloat4 r;
    r.x = fmaxf(a.x, b.x); r.y = fmaxf(a.y, b.y);
    r.z = fmaxf(a.z, b.z); r.w = fmaxf(a.w, b.w);
    return r;
}

__global__ __launch_bounds__(256) void sparsemax_quad(
    const float* __restrict__ x, float* __restrict__ out, long long n_rows) {
    __shared__ nfloat4 lds4[4][256];              // 4 KB per wave, wave-private
    const int lane = threadIdx.x & 63;
    const int w = threadIdx.x >> 6;
    const long long t = (long long)blockIdx.x * 4 + w;   // 16 rows per tile
    const long long row0 = t * 16;
    if (row0 >= n_rows) return;                   // whole-wave uniform exit
    nfloat4* W = lds4[w];

    const nfloat4* __restrict__ xv = reinterpret_cast<const nfloat4*>(x);
    nfloat4* __restrict__ ov = reinterpret_cast<nfloat4*>(out);
    const long long gbase = row0 * 16;            // f4 index of tile (256 f4)
    const long long f4max = n_rows * 16;
    const bool full = (row0 + 16) <= n_rows;

    // ---- stage in: global coalesced -> LDS swizzled ----
    if (full) {
#pragma unroll
        for (int i = 0; i < 4; ++i) {
            const int f = i * 64 + lane;          // linear f4 idx in tile
            const int r = f >> 4, c = f & 15;
            W[r * 16 + (c ^ (r & 7))] = xv[gbase + f];
        }
    } else {
#pragma unroll
        for (int i = 0; i < 4; ++i) {
            const int f = i * 64 + lane;
            const int r = f >> 4, c = f & 15;
            nfloat4 tv = {0.f, 0.f, 0.f, 0.f};
            if (gbase + f < f4max) tv = xv[gbase + f];
            W[r * 16 + (c ^ (r & 7))] = tv;
        }
    }
    asm volatile("" ::: "memory");   // phase order: writes before quad-reads

    const int qrow = lane >> 2;                   // tile-local row (0..15)
    const int q = lane & 3;                       // quarter within row
    const int s7 = qrow & 7;
    const int qb = qrow * 16;

    // ---- quad-read: quarter-row (16 floats) into pinned registers ----
#define QR(j) nfloat4 v##j = W[qb + ((q * 4 + j) ^ s7)];
    FOR4(QR)
#undef QR
#define PIN(j) asm volatile("" : "+v"(v##j.x), "+v"(v##j.y), "+v"(v##j.z), "+v"(v##j.w));
    FOR4(PIN)
#undef PIN

    // ---- row max (local 15 + 2-stage quad combine) -> tau0 = max - 1 ----
    nfloat4 m4 = v4max(v4max(v0, v1), v4max(v2, v3));
    float m = fmaxf(fmaxf(m4.x, m4.y), fmaxf(m4.z, m4.w));
    m = fmaxf(m, __shfl_xor(m, 1, 64));
    m = fmaxf(m, __shfl_xor(m, 2, 64));

    float tau = m - 1.0f;
    int cprev = -1;                 // force at least one iteration
    float rfin = 1.0f;
    for (int it = 0; it < 40; ++it) {
        // FROZEN per-value arithmetic: d = x - tau; max(d,0); count(d>0)
        float s0 = 0.f, s1 = 0.f;
        int c0 = 0, c1 = 0;
#define ACC(j) {                                              \
        const float d0 = v##j.x - tau, d1 = v##j.y - tau;     \
        const float d2 = v##j.z - tau, d3 = v##j.w - tau;     \
        s0 += fmaxf(d0, 0.f); c0 += (d0 > 0.f);               \
        s1 += fmaxf(d1, 0.f); c1 += (d1 > 0.f);               \
        s0 += fmaxf(d2, 0.f); c0 += (d2 > 0.f);               \
        s1 += fmaxf(d3, 0.f); c1 += (d3 > 0.f); }
        FOR4(ACC)
#undef ACC
        float s = s0 + s1;
        int c = c0 + c1;
        // quad combine: 2 DPP stages (commutative -> identical in quad)
        s += __shfl_xor(s, 1, 64);
        c += __shfl_xor(c, 1, 64);
        s += __shfl_xor(s, 2, 64);
        c += __shfl_xor(c, 2, 64);
        const bool done = (c == cprev);   // nested supports: count fixed
        cprev = c;
        const float rr = __builtin_amdgcn_rcpf((float)c);
        rfin = rr;
        tau += (s - 1.0f) * rr;           // idempotent once converged
        if (__all(done)) break;
    }
    const float tau_out = tau - rfin;     // reference double -1: tau* - 1/rho

    asm volatile("" ::: "memory");   // phase order: reads of originals below

    // ---- stage out: originals from LDS + tau via shfl -> coalesced NT store ----
    if (full) {
#pragma unroll
        for (int i = 0; i < 4; ++i) {
            const int f = i * 64 + lane;
            const int r = f >> 4, c = f & 15;
            const float tr = __shfl(tau_out, 4 * r, 64);  // lane 4r owns row r
            const nfloat4 vv = W[r * 16 + (c ^ (r & 7))];
            nfloat4 o;
            o.x = fmaxf(0.f, vv.x - tr);
            o.y = fmaxf(0.f, vv.y - tr);
            o.z = fmaxf(0.f, vv.z - tr);
            o.w = fmaxf(0.f, vv.w - tr);
            __builtin_nontemporal_store(o, &ov[gbase + f]);
        }
    } else {
#pragma unroll
        for (int i = 0; i < 4; ++i) {
            const int f = i * 64 + lane;
            const int r = f >> 4, c = f & 15;
            const float tr = __shfl(tau_out, 4 * r, 64);
            const nfloat4 vv = W[r * 16 + (c ^ (r & 7))];
            nfloat4 o;
            o.x = fmaxf(0.f, vv.x - tr);
            o.y = fmaxf(0.f, vv.y - tr);
            o.z = fmaxf(0.f, vv.z - tr);
            o.w = fmaxf(0.f, vv.w - tr);
            if (gbase + f < f4max)
                __builtin_nontemporal_store(o, &ov[gbase + f]);
        }
    }
}

extern "C" void kernel_launch(void* const* d_in, const int* in_sizes, int n_in,
                              void* d_out, int out_size, void* d_ws, size_t ws_size,
                              hipStream_t stream) {
    const float* x = (const float*)d_in[0];
    float* out = (float*)d_out;
    const long long n_rows = in_sizes[0] / 64;
    const long long ntiles = (n_rows + 15) / 16;

    const int block = 256;                        // 4 waves, 16KB LDS/block
    const long long grid = (ntiles + 3) / 4;      // 16384 for 1M rows
    sparsemax_quad<<<(int)grid, block, 0, stream>>>(x, out, n_rows);
}